// Round 1
// baseline (379.809 us; speedup 1.0000x reference)
//
#include <hip/hip_runtime.h>
#include <stdint.h>

#define Q_IN 33152
#define DIN 256
#define BATCH 4096
#define NTILES 1160   // padded K tiles of 32: 8 linear + sum_g 32*(8-g)
#define KCH 8
#define TPC 145       // NTILES / KCH

typedef _Float16 half8 __attribute__((ext_vector_type(8)));
typedef float floatx4 __attribute__((ext_vector_type(4)));

// ---------------------------------------------------------------------------
// K-tile table: tile T -> (i0, jbase). i0 = -1 means linear segment (scale=1).
// Segment for i0 covers j in [i0,256), front-padded to 32-aligned start.
__global__ void build_tab(uint32_t* tab) {
  int T = blockIdx.x * 256 + threadIdx.x;
  if (T >= NTILES) return;
  int i0, jb;
  if (T < 8) { i0 = -1; jb = 32 * T; }
  else {
    int Tp = T - 8;
    int g = 0, base = 0;
    for (; g < 8; ++g) { int sz = 32 * (8 - g); if (Tp < base + sz) break; base += sz; }
    int idx = Tp - base;
    int tl = 8 - g;          // tiles per segment in this group
    int s = idx / tl;
    int jt = idx - s * tl;
    i0 = 32 * g + s;
    jb = (i0 & ~31) + 32 * jt;
  }
  tab[T] = (((uint32_t)(uint16_t)(short)i0) << 16) | (uint32_t)(uint16_t)jb;
}

// ---------------------------------------------------------------------------
// Convert W (f32, [Oreal x Q_IN]) into f16 MFMA-fragment-tiled layout:
// Wt[(T*NTT+nt)*512 + l*8 + t] = W[o=nt*16+(l&15)][ksrc(T, (l>>4)*8+t)],
// zero for padded entries (j < i0) and o >= Oreal.
__global__ void convert_w(const float* __restrict__ W, _Float16* __restrict__ Wt,
                          const uint32_t* __restrict__ tab, int NTT, int Oreal) {
  int tid = blockIdx.x * 256 + threadIdx.x;
  if (tid >= NTILES * NTT * 64) return;
  int l = tid & 63;
  int nt = (tid >> 6) % NTT;
  int T = tid / (64 * NTT);
  int o = nt * 16 + (l & 15);
  int koff = (l >> 4) * 8;
  half8 v;
#pragma unroll
  for (int t = 0; t < 8; ++t) v[t] = (_Float16)0.f;
  if (o < Oreal) {
    uint32_t e = tab[T];
    int i0 = (short)(e >> 16);
    int jb = (int)(e & 0xFFFFu);
    const float* row = W + (size_t)o * Q_IN;
    if (i0 < 0) {
#pragma unroll
      for (int t = 0; t < 8; ++t) v[t] = (_Float16)row[jb + koff + t];
    } else {
      int qb = 256 + i0 * 256 - (i0 * (i0 - 1)) / 2 - i0;  // q = qb + j
#pragma unroll
      for (int t = 0; t < 8; ++t) {
        int j = jb + koff + t;
        if (j >= i0) v[t] = (_Float16)row[qb + j];
      }
    }
  }
  *(half8*)(Wt + (size_t)(T * NTT + nt) * 512 + l * 8) = v;
}

// ---------------------------------------------------------------------------
// Init accumulation targets with biases (atomicAdd adds GEMM on top).
__global__ void init_out(const float* __restrict__ b0, const float* __restrict__ b1,
                         const float* __restrict__ b2, float* __restrict__ h1,
                         float* __restrict__ h2, float* __restrict__ out) {
  int tid = blockIdx.x * 256 + threadIdx.x;   // 4096*256
  int b = tid >> 8, o = tid & 255;
  h1[tid] = b0[o];
  h2[tid] = b1[o];
  if (o < 10) out[b * 10 + o] = b2[o];
}

__device__ inline void gload_lds16(const void* g, void* l) {
  __builtin_amdgcn_global_load_lds(
      (const __attribute__((address_space(1))) uint32_t*)g,
      (__attribute__((address_space(3))) uint32_t*)l, 16, 0, 0);
}

// ---------------------------------------------------------------------------
// Quadratic-feature GEMM: out[b,o] += sum_k z[b,k] * W[o,k] over this WG's
// K-chunk. A-frags built in-register from LDS h-tile (XOR-swizzled), B staged
// via global_load_lds double-buffer with counted vmcnt.
template <int MT, int NTW, int MWAVES, int NWAVES, int NTT>
__global__ __launch_bounds__(512, 2) void qgemm(
    const float* __restrict__ hIn, const _Float16* __restrict__ Wt,
    float* __restrict__ outp, int out_stride, int Oreal,
    const uint32_t* __restrict__ gtab) {
  __shared__ _Float16 hT[128 * 256];       // 64 KB, row stride 512 B, col-swizzled
  __shared__ _Float16 bT[2][NTT * 512];    // double-buffered B tiles
  __shared__ uint32_t stab[TPC];

  const int tid = threadIdx.x;
  const int l = tid & 63;
  const int wid = tid >> 6;
  const int wgid = blockIdx.x;
  const int kch = wgid & 7;    // same kchunk -> same XCD (round-robin dispatch)
  const int rb = wgid >> 3;
  const int tbase = kch * TPC;

  // ---- stage h tile (rows rb*128..+128, f32 -> f16, XOR swizzle) ----
  {
    int r = tid >> 2, sg = tid & 3;
    const float* src = hIn + (size_t)(rb * 128 + r) * 256 + sg * 64;
    char* dstrow = (char*)hT + r * 512;
    int xo = (r & 7) << 4;
#pragma unroll
    for (int oc = 0; oc < 8; ++oc) {
      float4 f0 = *(const float4*)(src + oc * 8);
      float4 f1 = *(const float4*)(src + oc * 8 + 4);
      half8 hv;
      hv[0] = (_Float16)f0.x; hv[1] = (_Float16)f0.y;
      hv[2] = (_Float16)f0.z; hv[3] = (_Float16)f0.w;
      hv[4] = (_Float16)f1.x; hv[5] = (_Float16)f1.y;
      hv[6] = (_Float16)f1.z; hv[7] = (_Float16)f1.w;
      int cb = sg * 128 + oc * 16;
      *(half8*)(dstrow + (cb ^ xo)) = hv;
    }
  }
  if (tid < TPC) stab[tid] = gtab[tbase + tid];
  __syncthreads();  // full drain: hT + stab visible, vmcnt clean

  auto stage = [&](int buf, int tgl) {
    const char* gbase = (const char*)Wt + (size_t)tgl * (NTT * 1024);
    char* lbase = (char*)(&bT[buf][0]);
    for (int i = wid; i < NTT; i += 8)
      gload_lds16(gbase + i * 1024 + l * 16, lbase + i * 1024);
  };

  stage(0, tbase);

  floatx4 acc[MT][NTW];
#pragma unroll
  for (int mt = 0; mt < MT; ++mt)
#pragma unroll
    for (int nt = 0; nt < NTW; ++nt)
#pragma unroll
      for (int rg = 0; rg < 4; ++rg) acc[mt][nt][rg] = 0.f;

  const int wm = wid / NWAVES, wn = wid % NWAVES;
  int rowb[MT];
#pragma unroll
  for (int mt = 0; mt < MT; ++mt)
    rowb[mt] = (wm * (MT * 16) + mt * 16 + (l & 15)) * 512;
  const int koffB = (l >> 4) * 16;
  const int xorb = (l & 7) << 4;
  const int Lw = (NTT >= 8) ? (NTT / 8) : ((wid < NTT) ? 1 : 0);

  for (int t = 0; t < TPC; ++t) {
    const bool hasNext = (t + 1 < TPC);
    if (hasNext) stage((t + 1) & 1, tbase + t + 1);
    if (hasNext) {
      if (Lw == 2)      asm volatile("s_waitcnt vmcnt(2)" ::: "memory");
      else if (Lw == 1) asm volatile("s_waitcnt vmcnt(1)" ::: "memory");
      else              asm volatile("s_waitcnt vmcnt(0)" ::: "memory");
    } else {
      asm volatile("s_waitcnt vmcnt(0)" ::: "memory");
    }
    __builtin_amdgcn_s_barrier();
    __builtin_amdgcn_sched_barrier(0);

    uint32_t e = stab[t];
    int i0 = (short)(e >> 16);
    int jb = (int)(e & 0xFFFFu);
    int colx = (jb * 2 + koffB) ^ xorb;

    half8 a[MT];
#pragma unroll
    for (int mt = 0; mt < MT; ++mt)
      a[mt] = *(const half8*)((const char*)hT + rowb[mt] + colx);
    if (i0 >= 0) {
      int sb = (2 * i0) ^ xorb;
#pragma unroll
      for (int mt = 0; mt < MT; ++mt) {
        _Float16 sv = *(const _Float16*)((const char*)hT + rowb[mt] + sb);
        half8 s = {sv, sv, sv, sv, sv, sv, sv, sv};
        a[mt] = a[mt] * s;   // v_pk_mul_f16
      }
    }
    const char* bbase = (const char*)(&bT[t & 1][0]) + (wn * NTW) * 1024 + l * 16;
    half8 b[NTW];
#pragma unroll
    for (int nt = 0; nt < NTW; ++nt)
      b[nt] = *(const half8*)(bbase + nt * 1024);
#pragma unroll
    for (int mt = 0; mt < MT; ++mt)
#pragma unroll
      for (int nt = 0; nt < NTW; ++nt)
        acc[mt][nt] = __builtin_amdgcn_mfma_f32_16x16x32_f16(
            a[mt], b[nt], acc[mt][nt], 0, 0, 0);

    asm volatile("s_waitcnt lgkmcnt(0)" ::: "memory");
    __builtin_amdgcn_s_barrier();
    __builtin_amdgcn_sched_barrier(0);
  }

  // ---- epilogue: atomic accumulate (split-K partials) ----
  const int r0 = rb * 128 + wm * (MT * 16);
  const int c0 = wn * (NTW * 16);
#pragma unroll
  for (int mt = 0; mt < MT; ++mt) {
    int rbase = r0 + mt * 16 + (l >> 4) * 4;
#pragma unroll
    for (int nt = 0; nt < NTW; ++nt) {
      int c = c0 + nt * 16 + (l & 15);
      if (c < Oreal) {
#pragma unroll
        for (int rg = 0; rg < 4; ++rg)
          atomicAdd(&outp[(size_t)(rbase + rg) * out_stride + c], acc[mt][nt][rg]);
      }
    }
  }
}

// ---------------------------------------------------------------------------
extern "C" void kernel_launch(void* const* d_in, const int* in_sizes, int n_in,
                              void* d_out, int out_size, void* d_ws, size_t ws_size,
                              hipStream_t stream) {
  const float* x = (const float*)d_in[0];
  const float* W0 = (const float*)d_in[1];
  const float* b0 = (const float*)d_in[2];
  const float* W1 = (const float*)d_in[3];
  const float* b1 = (const float*)d_in[4];
  const float* W2 = (const float*)d_in[5];
  const float* b2 = (const float*)d_in[6];
  float* out = (float*)d_out;

  char* ws = (char*)d_ws;
  float* h1 = (float*)ws;                                  // 4 MB
  float* h2 = (float*)(ws + (4u << 20));                   // 4 MB
  _Float16* Wt = (_Float16*)(ws + (8u << 20));             // 37120*256*2 = 19,005,440 B
  uint32_t* tab = (uint32_t*)(ws + (8u << 20) + 19005440u);

  build_tab<<<(NTILES + 255) / 256, 256, 0, stream>>>(tab);
  init_out<<<4096, 256, 0, stream>>>(b0, b1, b2, h1, h2, out);

  // layer 0: x -> h1
  convert_w<<<(NTILES * 16 * 64) / 256, 256, 0, stream>>>(W0, Wt, tab, 16, 256);
  qgemm<4, 4, 2, 4, 16><<<256, 512, 0, stream>>>(x, Wt, h1, 256, 256, tab);
  // layer 1: h1 -> h2
  convert_w<<<(NTILES * 16 * 64) / 256, 256, 0, stream>>>(W1, Wt, tab, 16, 256);
  qgemm<4, 4, 2, 4, 16><<<256, 512, 0, stream>>>(h1, Wt, h2, 256, 256, tab);
  // layer 2: h2 -> out (O=10, padded to one 16-wide n-tile)
  convert_w<<<(NTILES * 1 * 64) / 256, 256, 0, stream>>>(W2, Wt, tab, 1, 10);
  qgemm<1, 1, 8, 1, 1><<<256, 512, 0, stream>>>(h2, Wt, out, 10, 10, tab);
}

// Round 2
// 304.406 us; speedup vs baseline: 1.2477x; 1.2477x over previous
//
#include <hip/hip_runtime.h>
#include <stdint.h>

#define Q_IN 33152
#define NTILES 1160   // 8 chunks x 145 tiles (1 linear + 144 quad)
#define TPC 145

typedef _Float16 half8 __attribute__((ext_vector_type(8)));
typedef float floatx4 __attribute__((ext_vector_type(4)));

// ---------------------------------------------------------------------------
// Tile table in EXECUTION order, chunk-major: T = kch*145 + tt.
// tt=0: linear segment (i0=-1, jb=32*kch). tt>=1: quad tile Q = kch*144+tt-1,
// enumerated group-major: groups (g, jt) with jb = 32*(g+jt), inner s=0..31,
// i0 = 32g+s. Same-jb runs are consecutive -> A-octets loop-invariant.
__global__ void build_tab(uint32_t* tab) {
  int T = blockIdx.x * 256 + threadIdx.x;
  if (T >= NTILES) return;
  int kch = T / TPC, tt = T % TPC;
  int i0, jb;
  if (tt == 0) { i0 = -1; jb = 32 * kch; }
  else {
    int Q = kch * 144 + (tt - 1);
    int grp = Q >> 5, s = Q & 31;
    int g = 0, base = 0;
    for (; g < 8; ++g) { int cnt = 8 - g; if (grp < base + cnt) break; base += cnt; }
    int jt = grp - base;
    i0 = 32 * g + s;
    jb = 32 * (g + jt);
  }
  tab[T] = (((uint32_t)(uint16_t)(short)i0) << 16) | (uint32_t)(uint16_t)jb;
}

// ---------------------------------------------------------------------------
// W (f32 [Oreal x Q_IN]) -> f16 MFMA-fragment-tiled Wt, tiles in exec order.
__global__ void convert_w(const float* __restrict__ W, _Float16* __restrict__ Wt,
                          const uint32_t* __restrict__ tab, int NTT, int Oreal) {
  int tid = blockIdx.x * 256 + threadIdx.x;
  if (tid >= NTILES * NTT * 64) return;
  int l = tid & 63;
  int nt = (tid >> 6) % NTT;
  int T = tid / (64 * NTT);
  int o = nt * 16 + (l & 15);
  int koff = (l >> 4) * 8;
  half8 v;
#pragma unroll
  for (int t = 0; t < 8; ++t) v[t] = (_Float16)0.f;
  if (o < Oreal) {
    uint32_t e = tab[T];
    int i0 = (short)(e >> 16);
    int jb = (int)(e & 0xFFFFu);
    const float* row = W + (size_t)o * Q_IN;
    if (i0 < 0) {
#pragma unroll
      for (int t = 0; t < 8; ++t) v[t] = (_Float16)row[jb + koff + t];
    } else {
      int qb = 256 + i0 * 256 - (i0 * (i0 - 1)) / 2 - i0;  // q = qb + j
#pragma unroll
      for (int t = 0; t < 8; ++t) {
        int j = jb + koff + t;
        if (j >= i0) v[t] = (_Float16)row[qb + j];
      }
    }
  }
  *(half8*)(Wt + (size_t)(T * NTT + nt) * 512 + l * 8) = v;
}

// ---------------------------------------------------------------------------
__global__ void init_out(const float* __restrict__ b0, const float* __restrict__ b1,
                         const float* __restrict__ b2, float* __restrict__ h1,
                         float* __restrict__ h2, float* __restrict__ out) {
  int tid = blockIdx.x * 256 + threadIdx.x;
  int b = tid >> 8, o = tid & 255;
  h1[tid] = b0[o];
  h2[tid] = b1[o];
  if (o < 10) out[b * 10 + o] = b2[o];
}

__device__ inline void gload_lds16(const void* g, void* l) {
  __builtin_amdgcn_global_load_lds(
      (const __attribute__((address_space(1))) uint32_t*)g,
      (__attribute__((address_space(3))) uint32_t*)l, 16, 0, 0);
}

__device__ inline floatx4 mfma16(half8 a, half8 b, floatx4 c) {
  return __builtin_amdgcn_mfma_f32_16x16x32_f16(a, b, c, 0, 0, 0);
}

// ---------------------------------------------------------------------------
// Main quadratic GEMM (layers 0/1): BM=128, N=256, 8 waves (1M x 8N),
// per-wave 128x32 (MT=8, NTW=2). A-octets + scales in registers (hoisted per
// jb-group / per 8-s block), B via 4-deep gload_lds ring, counted vmcnt(4),
// ONE barrier per tile.
__global__ __launch_bounds__(512, 2) void qgemm_main(
    const float* __restrict__ hIn, const _Float16* __restrict__ Wt,
    float* __restrict__ outp, const uint32_t* __restrict__ gtab) {
  __shared__ _Float16 hT[128 * 256];     // 64 KB, 512 B/row, XOR-swizzled cols
  __shared__ _Float16 bT[4][16 * 512];   // 4 x 16 KB ring

  const int tid = threadIdx.x;
  const int l = tid & 63;
  const int wid = tid >> 6;
  const int kch = blockIdx.x & 7;   // same-chunk WGs share an XCD (L2-resident Wt)
  const int rb = blockIdx.x >> 3;
  const int tbase = kch * TPC;

  auto stage = [&](int buf, int tgl) {
    const char* g = (const char*)Wt + (size_t)tgl * (16 * 1024);
    char* lb = (char*)(&bT[buf][0]);
#pragma unroll
    for (int i = 0; i < 2; ++i) {
      int t = wid + i * 8;
      gload_lds16(g + t * 1024 + l * 16, lb + t * 1024);
    }
  };
  stage(0, tbase);
  stage(1, tbase + 1);

  // ---- stage h tile (f32 -> f16, swizzle byte^=(row&7)<<4) ----
  {
    int r = tid >> 2, sg = tid & 3;
    const float* src = hIn + (size_t)(rb * 128 + r) * 256 + sg * 64;
    char* dst = (char*)hT + r * 512;
    int xo = (r & 7) << 4;
#pragma unroll
    for (int oc = 0; oc < 8; ++oc) {
      float4 f0 = *(const float4*)(src + oc * 8);
      float4 f1 = *(const float4*)(src + oc * 8 + 4);
      half8 hv;
      hv[0] = (_Float16)f0.x; hv[1] = (_Float16)f0.y;
      hv[2] = (_Float16)f0.z; hv[3] = (_Float16)f0.w;
      hv[4] = (_Float16)f1.x; hv[5] = (_Float16)f1.y;
      hv[6] = (_Float16)f1.z; hv[7] = (_Float16)f1.w;
      *(half8*)(dst + ((sg * 128 + oc * 16) ^ xo)) = hv;
    }
  }
  __syncthreads();

  floatx4 acc[8][2];
#pragma unroll
  for (int mt = 0; mt < 8; ++mt)
#pragma unroll
    for (int nt = 0; nt < 2; ++nt)
#pragma unroll
      for (int rg = 0; rg < 4; ++rg) acc[mt][nt][rg] = 0.f;

  const int wn = wid;  // NWAVES=8
  int rowb[8];
#pragma unroll
  for (int mt = 0; mt < 8; ++mt) rowb[mt] = (mt * 16 + (l & 15)) * 512;
  const int xorb = (l & 7) << 4;
  const int koffA = (l >> 4) * 16;
  const char* hTb = (const char*)hT;

  half8 a[8], sc[8];
  int prevjb;

  // ---- tile 0: linear (scale = 1) ----
  {
    uint32_t e0 = gtab[tbase];
    int jb = (int)(e0 & 0xFFFFu);
#pragma unroll
    for (int mt = 0; mt < 8; ++mt)
      a[mt] = *(const half8*)(hTb + rowb[mt] + ((jb * 2 + koffA) ^ xorb));
    stage(2, tbase + 2);
    asm volatile("s_waitcnt vmcnt(4)" ::: "memory");
    __builtin_amdgcn_s_barrier();
    __builtin_amdgcn_sched_barrier(0);
    const char* bb = (const char*)(&bT[0][0]) + wn * 2048 + l * 16;
    half8 b0 = *(const half8*)(bb);
    half8 b1 = *(const half8*)(bb + 1024);
    __builtin_amdgcn_s_setprio(1);
#pragma unroll
    for (int mt = 0; mt < 8; ++mt) {
      acc[mt][0] = mfma16(a[mt], b0, acc[mt][0]);
      acc[mt][1] = mfma16(a[mt], b1, acc[mt][1]);
    }
    __builtin_amdgcn_s_setprio(0);
    prevjb = jb;
  }

  // ---- 18 blocks of 8 quad tiles ----
  uint32_t e = gtab[tbase + 1];
  for (int u8 = 0; u8 < 18; ++u8) {
    uint32_t enext = (u8 < 17) ? gtab[tbase + 1 + (u8 + 1) * 8] : 0u;
    int i0b = (int)(e >> 16);        // block-start i0 (multiple of 8)
    int jb = (int)(e & 0xFFFFu);
    if (jb != prevjb) {
      prevjb = jb;
#pragma unroll
      for (int mt = 0; mt < 8; ++mt)
        a[mt] = *(const half8*)(hTb + rowb[mt] + ((jb * 2 + koffA) ^ xorb));
    }
#pragma unroll
    for (int mt = 0; mt < 8; ++mt)
      sc[mt] = *(const half8*)(hTb + rowb[mt] + ((i0b * 2) ^ xorb));

    const int ttb = 1 + u8 * 8;
#pragma unroll
    for (int s = 0; s < 8; ++s) {
      int tt = ttb + s;
      int rem = 144 - tt;
      if (rem >= 2) {
        stage((tt + 2) & 3, tbase + tt + 2);
        asm volatile("s_waitcnt vmcnt(4)" ::: "memory");
      } else if (rem == 1) {
        asm volatile("s_waitcnt vmcnt(2)" ::: "memory");
      } else {
        asm volatile("s_waitcnt vmcnt(0)" ::: "memory");
      }
      __builtin_amdgcn_s_barrier();
      __builtin_amdgcn_sched_barrier(0);
      const char* bb = (const char*)(&bT[tt & 3][0]) + wn * 2048 + l * 16;
      half8 b0 = *(const half8*)(bb);
      half8 b1 = *(const half8*)(bb + 1024);
      __builtin_amdgcn_s_setprio(1);
#pragma unroll
      for (int mt = 0; mt < 8; ++mt) {
        _Float16 sv = sc[mt][s];
        half8 sb = {sv, sv, sv, sv, sv, sv, sv, sv};
        half8 as_ = a[mt] * sb;   // v_pk_mul_f16
        acc[mt][0] = mfma16(as_, b0, acc[mt][0]);
        acc[mt][1] = mfma16(as_, b1, acc[mt][1]);
      }
      __builtin_amdgcn_s_setprio(0);
    }
    e = enext;
  }

  // ---- epilogue: split-K atomic accumulate ----
  const int r0 = rb * 128;
  const int c0 = wn * 32;
#pragma unroll
  for (int mt = 0; mt < 8; ++mt) {
    int rbase = r0 + mt * 16 + (l >> 4) * 4;
#pragma unroll
    for (int nt = 0; nt < 2; ++nt) {
      int c = c0 + nt * 16 + (l & 15);
#pragma unroll
      for (int rg = 0; rg < 4; ++rg)
        atomicAdd(&outp[(size_t)(rbase + rg) * 256 + c], acc[mt][nt][rg]);
    }
  }
}

// ---------------------------------------------------------------------------
// Layer 2 (O=10, one 16-wide n-tile): B straight global->reg (L2 broadcast),
// no bT, no barriers. 8 waves each own 16 rows (MT=1).
__global__ __launch_bounds__(512, 2) void qgemm_small(
    const float* __restrict__ hIn, const _Float16* __restrict__ Wt,
    float* __restrict__ outp, const uint32_t* __restrict__ gtab) {
  __shared__ _Float16 hT[128 * 256];
  const int tid = threadIdx.x;
  const int l = tid & 63;
  const int wid = tid >> 6;
  const int kch = blockIdx.x & 7;
  const int rb = blockIdx.x >> 3;
  const int tbase = kch * TPC;

  {
    int r = tid >> 2, sg = tid & 3;
    const float* src = hIn + (size_t)(rb * 128 + r) * 256 + sg * 64;
    char* dst = (char*)hT + r * 512;
    int xo = (r & 7) << 4;
#pragma unroll
    for (int oc = 0; oc < 8; ++oc) {
      float4 f0 = *(const float4*)(src + oc * 8);
      float4 f1 = *(const float4*)(src + oc * 8 + 4);
      half8 hv;
      hv[0] = (_Float16)f0.x; hv[1] = (_Float16)f0.y;
      hv[2] = (_Float16)f0.z; hv[3] = (_Float16)f0.w;
      hv[4] = (_Float16)f1.x; hv[5] = (_Float16)f1.y;
      hv[6] = (_Float16)f1.z; hv[7] = (_Float16)f1.w;
      *(half8*)(dst + ((sg * 128 + oc * 16) ^ xo)) = hv;
    }
  }
  __syncthreads();

  floatx4 acc;
#pragma unroll
  for (int rg = 0; rg < 4; ++rg) acc[rg] = 0.f;

  const int rowb = (wid * 16 + (l & 15)) * 512;
  const int xorb = (l & 7) << 4;
  const int koffA = (l >> 4) * 16;
  const char* hTb = (const char*)hT;

  half8 a, sc;
  int prevjb;

  {
    uint32_t e0 = gtab[tbase];
    int jb = (int)(e0 & 0xFFFFu);
    a = *(const half8*)(hTb + rowb + ((jb * 2 + koffA) ^ xorb));
    half8 b = *(const half8*)(Wt + (size_t)tbase * 512 + l * 8);
    acc = mfma16(a, b, acc);
    prevjb = jb;
  }

  uint32_t e = gtab[tbase + 1];
  for (int u8 = 0; u8 < 18; ++u8) {
    uint32_t enext = (u8 < 17) ? gtab[tbase + 1 + (u8 + 1) * 8] : 0u;
    int i0b = (int)(e >> 16);
    int jb = (int)(e & 0xFFFFu);
    if (jb != prevjb) {
      prevjb = jb;
      a = *(const half8*)(hTb + rowb + ((jb * 2 + koffA) ^ xorb));
    }
    sc = *(const half8*)(hTb + rowb + ((i0b * 2) ^ xorb));
    const int ttb = tbase + 1 + u8 * 8;
    half8 bq[8];
#pragma unroll
    for (int s = 0; s < 8; ++s)
      bq[s] = *(const half8*)(Wt + (size_t)(ttb + s) * 512 + l * 8);
#pragma unroll
    for (int s = 0; s < 8; ++s) {
      _Float16 sv = sc[s];
      half8 sb = {sv, sv, sv, sv, sv, sv, sv, sv};
      acc = mfma16(a * sb, bq[s], acc);
    }
    e = enext;
  }

  const int r0 = rb * 128 + wid * 16 + (l >> 4) * 4;
  const int c = l & 15;
  if (c < 10) {
#pragma unroll
    for (int rg = 0; rg < 4; ++rg)
      atomicAdd(&outp[(size_t)(r0 + rg) * 10 + c], acc[rg]);
  }
}

// ---------------------------------------------------------------------------
extern "C" void kernel_launch(void* const* d_in, const int* in_sizes, int n_in,
                              void* d_out, int out_size, void* d_ws, size_t ws_size,
                              hipStream_t stream) {
  const float* x = (const float*)d_in[0];
  const float* W0 = (const float*)d_in[1];
  const float* b0 = (const float*)d_in[2];
  const float* W1 = (const float*)d_in[3];
  const float* b1 = (const float*)d_in[4];
  const float* W2 = (const float*)d_in[5];
  const float* b2 = (const float*)d_in[6];
  float* out = (float*)d_out;

  char* ws = (char*)d_ws;
  float* h1 = (float*)ws;                                  // 4 MB
  float* h2 = (float*)(ws + (4u << 20));                   // 4 MB
  _Float16* Wt = (_Float16*)(ws + (8u << 20));             // 19,005,440 B
  uint32_t* tab = (uint32_t*)(ws + (8u << 20) + 19005440u);

  build_tab<<<(NTILES + 255) / 256, 256, 0, stream>>>(tab);
  init_out<<<4096, 256, 0, stream>>>(b0, b1, b2, h1, h2, out);

  // layer 0
  convert_w<<<(NTILES * 16 * 64) / 256, 256, 0, stream>>>(W0, Wt, tab, 16, 256);
  qgemm_main<<<256, 512, 0, stream>>>(x, Wt, h1, tab);
  // layer 1
  convert_w<<<(NTILES * 16 * 64) / 256, 256, 0, stream>>>(W1, Wt, tab, 16, 256);
  qgemm_main<<<256, 512, 0, stream>>>(h1, Wt, h2, tab);
  // layer 2
  convert_w<<<(NTILES * 1 * 64 + 255) / 256, 256, 0, stream>>>(W2, Wt, tab, 1, 10);
  qgemm_small<<<256, 512, 0, stream>>>(h2, Wt, out, tab);
}

// Round 3
// 258.717 us; speedup vs baseline: 1.4681x; 1.1766x over previous
//
#include <hip/hip_runtime.h>
#include <stdint.h>

#define Q_IN 33152
#define NTILES 1160   // 8 chunks x 145 tiles (1 linear + 144 quad)
#define TPC 145

typedef _Float16 half8 __attribute__((ext_vector_type(8)));
typedef float floatx4 __attribute__((ext_vector_type(4)));

// ---------------------------------------------------------------------------
// Tile table in EXECUTION order, chunk-major: T = kch*145 + tt.
// tt=0: linear segment (i0=-1, jb=32*kch). tt>=1: quad tile Q = kch*144+tt-1,
// group-major (g, jt) with jb = 32*(g+jt), inner s=0..31, i0 = 32g+s.
__global__ void build_tab(uint32_t* tab) {
  int T = blockIdx.x * 256 + threadIdx.x;
  if (T >= NTILES) return;
  int kch = T / TPC, tt = T % TPC;
  int i0, jb;
  if (tt == 0) { i0 = -1; jb = 32 * kch; }
  else {
    int Q = kch * 144 + (tt - 1);
    int grp = Q >> 5, s = Q & 31;
    int g = 0, base = 0;
    for (; g < 8; ++g) { int cnt = 8 - g; if (grp < base + cnt) break; base += cnt; }
    int jt = grp - base;
    i0 = 32 * g + s;
    jb = 32 * (g + jt);
  }
  tab[T] = (((uint32_t)(uint16_t)(short)i0) << 16) | (uint32_t)(uint16_t)jb;
}

// ---------------------------------------------------------------------------
// W (f32 [Oreal x Q_IN]) -> f16 MFMA-fragment-tiled Wt, tiles in exec order.
__global__ void convert_w(const float* __restrict__ W, _Float16* __restrict__ Wt,
                          const uint32_t* __restrict__ tab, int NTT, int Oreal) {
  int tid = blockIdx.x * 256 + threadIdx.x;
  if (tid >= NTILES * NTT * 64) return;
  int l = tid & 63;
  int nt = (tid >> 6) % NTT;
  int T = tid / (64 * NTT);
  int o = nt * 16 + (l & 15);
  int koff = (l >> 4) * 8;
  half8 v;
#pragma unroll
  for (int t = 0; t < 8; ++t) v[t] = (_Float16)0.f;
  if (o < Oreal) {
    uint32_t e = tab[T];
    int i0 = (short)(e >> 16);
    int jb = (int)(e & 0xFFFFu);
    const float* row = W + (size_t)o * Q_IN;
    if (i0 < 0) {
#pragma unroll
      for (int t = 0; t < 8; ++t) v[t] = (_Float16)row[jb + koff + t];
    } else {
      int qb = 256 + i0 * 256 - (i0 * (i0 - 1)) / 2 - i0;  // q = qb + j
#pragma unroll
      for (int t = 0; t < 8; ++t) {
        int j = jb + koff + t;
        if (j >= i0) v[t] = (_Float16)row[qb + j];
      }
    }
  }
  *(half8*)(Wt + (size_t)(T * NTT + nt) * 512 + l * 8) = v;
}

// ---------------------------------------------------------------------------
__global__ void init_out(const float* __restrict__ b0, const float* __restrict__ b1,
                         const float* __restrict__ b2, float* __restrict__ h1,
                         float* __restrict__ h2, float* __restrict__ out) {
  int tid = blockIdx.x * 256 + threadIdx.x;
  int b = tid >> 8, o = tid & 255;
  h1[tid] = b0[o];
  h2[tid] = b1[o];
  if (o < 10) out[b * 10 + o] = b2[o];
}

__device__ inline floatx4 mfma16(half8 a, half8 b, floatx4 c) {
  return __builtin_amdgcn_mfma_f32_16x16x32_f16(a, b, c, 0, 0, 0);
}

// ---------------------------------------------------------------------------
// Main quadratic GEMM (layers 0/1): BM=128, N=256, 8 waves (1M x 8N),
// per-wave 128x32 (MT=8, NTW=2). A-octets + scales in registers (hoisted per
// jb-group / per 8-s block). B loaded global->registers (waves own disjoint
// columns; L2 provides the inter-WG reuse) -> NO barriers in the K-loop.
__global__ __launch_bounds__(512, 1) void qgemm_main(
    const float* __restrict__ hIn, const _Float16* __restrict__ Wt,
    float* __restrict__ outp, const uint32_t* __restrict__ gtab) {
  __shared__ _Float16 hT[128 * 256];     // 64 KB, 512 B/row, XOR-swizzled cols

  const int tid = threadIdx.x;
  const int l = tid & 63;
  const int wid = tid >> 6;
  const int kch = blockIdx.x & 7;   // same-chunk WGs share an XCD (L2-resident Wt)
  const int rb = blockIdx.x >> 3;
  const int tbase = kch * TPC;

  // ---- stage h tile (f32 -> f16, swizzle byte^=(row&7)<<4) ----
  {
    int r = tid >> 2, sg = tid & 3;
    const float* src = hIn + (size_t)(rb * 128 + r) * 256 + sg * 64;
    char* dst = (char*)hT + r * 512;
    int xo = (r & 7) << 4;
#pragma unroll
    for (int oc = 0; oc < 8; ++oc) {
      float4 f0 = *(const float4*)(src + oc * 8);
      float4 f1 = *(const float4*)(src + oc * 8 + 4);
      half8 hv;
      hv[0] = (_Float16)f0.x; hv[1] = (_Float16)f0.y;
      hv[2] = (_Float16)f0.z; hv[3] = (_Float16)f0.w;
      hv[4] = (_Float16)f1.x; hv[5] = (_Float16)f1.y;
      hv[6] = (_Float16)f1.z; hv[7] = (_Float16)f1.w;
      *(half8*)(dst + ((sg * 128 + oc * 16) ^ xo)) = hv;
    }
  }
  __syncthreads();

  floatx4 acc[8][2];
#pragma unroll
  for (int mt = 0; mt < 8; ++mt)
#pragma unroll
    for (int nt = 0; nt < 2; ++nt)
#pragma unroll
      for (int rg = 0; rg < 4; ++rg) acc[mt][nt][rg] = 0.f;

  int rowb[8];
#pragma unroll
  for (int mt = 0; mt < 8; ++mt) rowb[mt] = (mt * 16 + (l & 15)) * 512;
  const int xorb = (l & 7) << 4;
  const int koffA = (l >> 4) * 16;
  const char* hTb = (const char*)hT;
  // B base for this wave: tile stride 16 KB, wave column slice wid*2048 + l*16
  const char* bp = (const char*)Wt + (size_t)tbase * 16384 + wid * 2048 + l * 16;

  half8 a[8], sc[8];
  int prevjb;

  // ---- tile 0: linear (scale = 1) ----
  {
    uint32_t e0 = gtab[tbase];
    int jb = (int)(e0 & 0xFFFFu);
    half8 b0 = *(const half8*)(bp);
    half8 b1 = *(const half8*)(bp + 1024);
#pragma unroll
    for (int mt = 0; mt < 8; ++mt)
      a[mt] = *(const half8*)(hTb + rowb[mt] + ((jb * 2 + koffA) ^ xorb));
#pragma unroll
    for (int mt = 0; mt < 8; ++mt) {
      acc[mt][0] = mfma16(a[mt], b0, acc[mt][0]);
      acc[mt][1] = mfma16(a[mt], b1, acc[mt][1]);
    }
    prevjb = jb;
  }

  // ---- 18 blocks of 8 quad tiles; 16 B-loads batched up-front per block ----
  uint32_t e = gtab[tbase + 1];
  for (int u8 = 0; u8 < 18; ++u8) {
    uint32_t enext = (u8 < 17) ? gtab[tbase + 1 + (u8 + 1) * 8] : 0u;
    const char* bpb = bp + (size_t)(1 + u8 * 8) * 16384;
    half8 bq[8][2];
#pragma unroll
    for (int s = 0; s < 8; ++s) {
      bq[s][0] = *(const half8*)(bpb + s * 16384);
      bq[s][1] = *(const half8*)(bpb + s * 16384 + 1024);
    }
    int i0b = (int)(e >> 16);        // block-start i0 (multiple of 8)
    int jb = (int)(e & 0xFFFFu);
#pragma unroll
    for (int mt = 0; mt < 8; ++mt)
      sc[mt] = *(const half8*)(hTb + rowb[mt] + ((i0b * 2) ^ xorb));
    if (jb != prevjb) {
      prevjb = jb;
#pragma unroll
      for (int mt = 0; mt < 8; ++mt)
        a[mt] = *(const half8*)(hTb + rowb[mt] + ((jb * 2 + koffA) ^ xorb));
    }
#pragma unroll
    for (int s = 0; s < 8; ++s) {
#pragma unroll
      for (int mt = 0; mt < 8; ++mt) {
        _Float16 sv = sc[mt][s];
        half8 sb = {sv, sv, sv, sv, sv, sv, sv, sv};
        half8 as_ = a[mt] * sb;   // v_pk_mul_f16
        acc[mt][0] = mfma16(as_, bq[s][0], acc[mt][0]);
        acc[mt][1] = mfma16(as_, bq[s][1], acc[mt][1]);
      }
    }
    e = enext;
  }

  // ---- epilogue: split-K atomic accumulate ----
  const int r0 = rb * 128;
  const int c0 = wid * 32;
#pragma unroll
  for (int mt = 0; mt < 8; ++mt) {
    int rbase = r0 + mt * 16 + (l >> 4) * 4;
#pragma unroll
    for (int nt = 0; nt < 2; ++nt) {
      int c = c0 + nt * 16 + (l & 15);
#pragma unroll
      for (int rg = 0; rg < 4; ++rg)
        atomicAdd(&outp[(size_t)(rbase + rg) * 256 + c], acc[mt][nt][rg]);
    }
  }
}

// ---------------------------------------------------------------------------
// Layer 2 (O=10, one 16-wide n-tile): B global->reg, no barriers in loop.
__global__ __launch_bounds__(512, 2) void qgemm_small(
    const float* __restrict__ hIn, const _Float16* __restrict__ Wt,
    float* __restrict__ outp, const uint32_t* __restrict__ gtab) {
  __shared__ _Float16 hT[128 * 256];
  const int tid = threadIdx.x;
  const int l = tid & 63;
  const int wid = tid >> 6;
  const int kch = blockIdx.x & 7;
  const int rb = blockIdx.x >> 3;
  const int tbase = kch * TPC;

  {
    int r = tid >> 2, sg = tid & 3;
    const float* src = hIn + (size_t)(rb * 128 + r) * 256 + sg * 64;
    char* dst = (char*)hT + r * 512;
    int xo = (r & 7) << 4;
#pragma unroll
    for (int oc = 0; oc < 8; ++oc) {
      float4 f0 = *(const float4*)(src + oc * 8);
      float4 f1 = *(const float4*)(src + oc * 8 + 4);
      half8 hv;
      hv[0] = (_Float16)f0.x; hv[1] = (_Float16)f0.y;
      hv[2] = (_Float16)f0.z; hv[3] = (_Float16)f0.w;
      hv[4] = (_Float16)f1.x; hv[5] = (_Float16)f1.y;
      hv[6] = (_Float16)f1.z; hv[7] = (_Float16)f1.w;
      *(half8*)(dst + ((sg * 128 + oc * 16) ^ xo)) = hv;
    }
  }
  __syncthreads();

  floatx4 acc;
#pragma unroll
  for (int rg = 0; rg < 4; ++rg) acc[rg] = 0.f;

  const int rowb = (wid * 16 + (l & 15)) * 512;
  const int xorb = (l & 7) << 4;
  const int koffA = (l >> 4) * 16;
  const char* hTb = (const char*)hT;

  half8 a, sc;
  int prevjb;

  {
    uint32_t e0 = gtab[tbase];
    int jb = (int)(e0 & 0xFFFFu);
    a = *(const half8*)(hTb + rowb + ((jb * 2 + koffA) ^ xorb));
    half8 b = *(const half8*)(Wt + (size_t)tbase * 512 + l * 8);
    acc = mfma16(a, b, acc);
    prevjb = jb;
  }

  uint32_t e = gtab[tbase + 1];
  for (int u8 = 0; u8 < 18; ++u8) {
    uint32_t enext = (u8 < 17) ? gtab[tbase + 1 + (u8 + 1) * 8] : 0u;
    int i0b = (int)(e >> 16);
    int jb = (int)(e & 0xFFFFu);
    const int ttb = tbase + 1 + u8 * 8;
    half8 bq[8];
#pragma unroll
    for (int s = 0; s < 8; ++s)
      bq[s] = *(const half8*)(Wt + (size_t)(ttb + s) * 512 + l * 8);
    if (jb != prevjb) {
      prevjb = jb;
      a = *(const half8*)(hTb + rowb + ((jb * 2 + koffA) ^ xorb));
    }
    sc = *(const half8*)(hTb + rowb + ((i0b * 2) ^ xorb));
#pragma unroll
    for (int s = 0; s < 8; ++s) {
      _Float16 sv = sc[s];
      half8 sb = {sv, sv, sv, sv, sv, sv, sv, sv};
      acc = mfma16(a * sb, bq[s], acc);
    }
    e = enext;
  }

  const int r0 = rb * 128 + wid * 16 + (l >> 4) * 4;
  const int c = l & 15;
  if (c < 10) {
#pragma unroll
    for (int rg = 0; rg < 4; ++rg)
      atomicAdd(&outp[(size_t)(r0 + rg) * 10 + c], acc[rg]);
  }
}

// ---------------------------------------------------------------------------
extern "C" void kernel_launch(void* const* d_in, const int* in_sizes, int n_in,
                              void* d_out, int out_size, void* d_ws, size_t ws_size,
                              hipStream_t stream) {
  const float* x = (const float*)d_in[0];
  const float* W0 = (const float*)d_in[1];
  const float* b0 = (const float*)d_in[2];
  const float* W1 = (const float*)d_in[3];
  const float* b1 = (const float*)d_in[4];
  const float* W2 = (const float*)d_in[5];
  const float* b2 = (const float*)d_in[6];
  float* out = (float*)d_out;

  char* ws = (char*)d_ws;
  float* h1 = (float*)ws;                                  // 4 MB
  float* h2 = (float*)(ws + (4u << 20));                   // 4 MB
  _Float16* Wt = (_Float16*)(ws + (8u << 20));             // 19,005,440 B
  uint32_t* tab = (uint32_t*)(ws + (8u << 20) + 19005440u);

  build_tab<<<(NTILES + 255) / 256, 256, 0, stream>>>(tab);
  init_out<<<4096, 256, 0, stream>>>(b0, b1, b2, h1, h2, out);

  // layer 0
  convert_w<<<(NTILES * 16 * 64) / 256, 256, 0, stream>>>(W0, Wt, tab, 16, 256);
  qgemm_main<<<256, 512, 0, stream>>>(x, Wt, h1, tab);
  // layer 1
  convert_w<<<(NTILES * 16 * 64) / 256, 256, 0, stream>>>(W1, Wt, tab, 16, 256);
  qgemm_main<<<256, 512, 0, stream>>>(h1, Wt, h2, tab);
  // layer 2
  convert_w<<<(NTILES * 1 * 64 + 255) / 256, 256, 0, stream>>>(W2, Wt, tab, 1, 10);
  qgemm_small<<<256, 512, 0, stream>>>(h2, Wt, out, tab);
}

// Round 4
// 253.575 us; speedup vs baseline: 1.4978x; 1.0203x over previous
//
#include <hip/hip_runtime.h>
#include <stdint.h>

#define Q_IN 33152
#define NTILES 1160   // 8 chunks x 145 tiles (1 linear + 144 quad)
#define TPC 145

typedef _Float16 half8 __attribute__((ext_vector_type(8)));
typedef float floatx4 __attribute__((ext_vector_type(4)));
typedef uint32_t uint4v __attribute__((ext_vector_type(4)));

// ---------------------------------------------------------------------------
// Tile table in EXECUTION order, chunk-major: T = kch*145 + tt.
// tt=0: linear segment (i0=-1, jb=32*kch). tt>=1: quad tile Q = kch*144+tt-1,
// group-major (g, jt) with jb = 32*(g+jt), inner s=0..31, i0 = 32g+s.
__global__ void build_tab(uint32_t* tab) {
  int T = blockIdx.x * 256 + threadIdx.x;
  if (T >= NTILES) return;
  int kch = T / TPC, tt = T % TPC;
  int i0, jb;
  if (tt == 0) { i0 = -1; jb = 32 * kch; }
  else {
    int Q = kch * 144 + (tt - 1);
    int grp = Q >> 5, s = Q & 31;
    int g = 0, base = 0;
    for (; g < 8; ++g) { int cnt = 8 - g; if (grp < base + cnt) break; base += cnt; }
    int jt = grp - base;
    i0 = 32 * g + s;
    jb = 32 * (g + jt);
  }
  tab[T] = (((uint32_t)(uint16_t)(short)i0) << 16) | (uint32_t)(uint16_t)jb;
}

// ---------------------------------------------------------------------------
// W (f32 [Oreal x Q_IN]) -> f16 MFMA-fragment-tiled Wt, tiles in exec order.
__global__ void convert_w(const float* __restrict__ W, _Float16* __restrict__ Wt,
                          const uint32_t* __restrict__ tab, int NTT, int Oreal) {
  int tid = blockIdx.x * 256 + threadIdx.x;
  if (tid >= NTILES * NTT * 64) return;
  int l = tid & 63;
  int nt = (tid >> 6) % NTT;
  int T = tid / (64 * NTT);
  int o = nt * 16 + (l & 15);
  int koff = (l >> 4) * 8;
  half8 v;
#pragma unroll
  for (int t = 0; t < 8; ++t) v[t] = (_Float16)0.f;
  if (o < Oreal) {
    uint32_t e = tab[T];
    int i0 = (short)(e >> 16);
    int jb = (int)(e & 0xFFFFu);
    const float* row = W + (size_t)o * Q_IN;
    if (i0 < 0) {
#pragma unroll
      for (int t = 0; t < 8; ++t) v[t] = (_Float16)row[jb + koff + t];
    } else {
      int qb = 256 + i0 * 256 - (i0 * (i0 - 1)) / 2 - i0;  // q = qb + j
#pragma unroll
      for (int t = 0; t < 8; ++t) {
        int j = jb + koff + t;
        if (j >= i0) v[t] = (_Float16)row[qb + j];
      }
    }
  }
  *(half8*)(Wt + (size_t)(T * NTT + nt) * 512 + l * 8) = v;
}

// ---------------------------------------------------------------------------
__global__ void init_out(const float* __restrict__ b0, const float* __restrict__ b1,
                         const float* __restrict__ b2, float* __restrict__ h1,
                         float* __restrict__ h2, float* __restrict__ out) {
  int tid = blockIdx.x * 256 + threadIdx.x;
  int b = tid >> 8, o = tid & 255;
  h1[tid] = b0[o];
  h2[tid] = b1[o];
  if (o < 10) out[b * 10 + o] = b2[o];
}

__device__ inline floatx4 mfma16(half8 a, half8 b, floatx4 c) {
  return __builtin_amdgcn_mfma_f32_16x16x32_f16(a, b, c, 0, 0, 0);
}

__device__ inline half8 splat_mul(half8 a, uint32_t sdw, uint32_t sel) {
  uint32_t w = __builtin_amdgcn_perm(sdw, sdw, sel);  // 16-bit broadcast, 1 VALU
  uint4v wv = {w, w, w, w};
  return a * __builtin_bit_cast(half8, wv);           // 4x v_pk_mul_f16, shared src
}

// ---------------------------------------------------------------------------
// Main quadratic GEMM (layers 0/1): BM=128, N=256, 8 waves (1M x 8N),
// per-wave 128x32 (MT=8, NTW=2). A-octets + scales in registers. B loaded
// global->reg via saddr-form loads, 2-group register pipeline (16 loads in
// flight), NO barriers in the K-loop.
__global__ __launch_bounds__(512, 2) void qgemm_main(
    const float* __restrict__ hIn, const _Float16* __restrict__ Wt,
    float* __restrict__ outp, const uint32_t* __restrict__ gtab) {
  __shared__ _Float16 hT[128 * 256];     // 64 KB, 512 B/row, XOR-swizzled cols

  const int tid = threadIdx.x;
  const int l = tid & 63;
  const int wid = tid >> 6;
  const int kch = blockIdx.x & 7;   // same-chunk WGs share an XCD (L2-resident Wt)
  const int rb = blockIdx.x >> 3;
  const int tbase = kch * TPC;

  // uniform (SGPR) B base + 32-bit lane offset -> saddr-form global loads
  const char* gb = (const char*)Wt + (size_t)tbase * 16384;
  const uint32_t lo = (uint32_t)(wid * 2048 + l * 16);

  // issue linear-tile B + block-0 groups up front (latency hides under staging)
  half8 blin0 = *(const half8*)(gb + lo);
  half8 blin1 = *(const half8*)(gb + (lo + 1024));
  const char* gq = gb + 16384;           // quad tiles start
  half8 gA[4][2], gB[4][2];
#pragma unroll
  for (int sp = 0; sp < 4; ++sp) {
    gA[sp][0] = *(const half8*)(gq + (lo + sp * 16384u));
    gA[sp][1] = *(const half8*)(gq + (lo + sp * 16384u + 1024u));
  }
#pragma unroll
  for (int sp = 0; sp < 4; ++sp) {
    gB[sp][0] = *(const half8*)(gq + (lo + (4 + sp) * 16384u));
    gB[sp][1] = *(const half8*)(gq + (lo + (4 + sp) * 16384u + 1024u));
  }

  // ---- stage h tile (f32 -> f16, swizzle byte^=(row&7)<<4) ----
  {
    int r = tid >> 2, sg = tid & 3;
    const float* src = hIn + (size_t)(rb * 128 + r) * 256 + sg * 64;
    char* dst = (char*)hT + r * 512;
    int xo = (r & 7) << 4;
#pragma unroll
    for (int oc = 0; oc < 8; ++oc) {
      float4 f0 = *(const float4*)(src + oc * 8);
      float4 f1 = *(const float4*)(src + oc * 8 + 4);
      half8 hv;
      hv[0] = (_Float16)f0.x; hv[1] = (_Float16)f0.y;
      hv[2] = (_Float16)f0.z; hv[3] = (_Float16)f0.w;
      hv[4] = (_Float16)f1.x; hv[5] = (_Float16)f1.y;
      hv[6] = (_Float16)f1.z; hv[7] = (_Float16)f1.w;
      *(half8*)(dst + ((sg * 128 + oc * 16) ^ xo)) = hv;
    }
  }
  __syncthreads();

  floatx4 acc[8][2];
#pragma unroll
  for (int mt = 0; mt < 8; ++mt)
#pragma unroll
    for (int nt = 0; nt < 2; ++nt)
#pragma unroll
      for (int rg = 0; rg < 4; ++rg) acc[mt][nt][rg] = 0.f;

  int rowb[8];
#pragma unroll
  for (int mt = 0; mt < 8; ++mt) rowb[mt] = (mt * 16 + (l & 15)) * 512;
  const int xorb = (l & 7) << 4;
  const int koffA = (l >> 4) * 16;
  const char* hTb = (const char*)hT;

  half8 a[8];
  int prevjb;

  // ---- tile 0: linear (scale = 1) ----
  {
    uint32_t e0 = gtab[tbase];
    int jb = (int)(e0 & 0xFFFFu);
#pragma unroll
    for (int mt = 0; mt < 8; ++mt)
      a[mt] = *(const half8*)(hTb + rowb[mt] + ((jb * 2 + koffA) ^ xorb));
#pragma unroll
    for (int mt = 0; mt < 8; ++mt) {
      acc[mt][0] = mfma16(a[mt], blin0, acc[mt][0]);
      acc[mt][1] = mfma16(a[mt], blin1, acc[mt][1]);
    }
    prevjb = jb;
  }

  // ---- 18 blocks of 8 quad tiles; 2-group register pipeline ----
  uint32_t e = gtab[tbase + 1];
  for (int b = 0; b < 18; ++b) {
    uint32_t enext = (b < 17) ? gtab[tbase + 1 + (b + 1) * 8] : 0u;
    int i0b = (int)(e >> 16);        // block-start i0 (multiple of 8)
    int jb = (int)(e & 0xFFFFu);
    uint4v scu[8];
#pragma unroll
    for (int mt = 0; mt < 8; ++mt)
      scu[mt] = *(const uint4v*)(hTb + rowb[mt] + ((i0b * 2) ^ xorb));
    if (jb != prevjb) {
      prevjb = jb;
#pragma unroll
      for (int mt = 0; mt < 8; ++mt)
        a[mt] = *(const half8*)(hTb + rowb[mt] + ((jb * 2 + koffA) ^ xorb));
    }
    const char* gqn = gq + 131072;

    // consume A-group (tiles 0-3)
#pragma unroll
    for (int sp = 0; sp < 4; ++sp) {
      uint32_t sel = (sp & 1) ? 0x03020302u : 0x01000100u;
#pragma unroll
      for (int mt = 0; mt < 8; ++mt) {
        half8 as_ = splat_mul(a[mt], scu[mt][sp >> 1], sel);
        acc[mt][0] = mfma16(as_, gA[sp][0], acc[mt][0]);
        acc[mt][1] = mfma16(as_, gA[sp][1], acc[mt][1]);
      }
    }
    // refill A-group for next block
    if (b < 17) {
#pragma unroll
      for (int sp = 0; sp < 4; ++sp) {
        gA[sp][0] = *(const half8*)(gqn + (lo + sp * 16384u));
        gA[sp][1] = *(const half8*)(gqn + (lo + sp * 16384u + 1024u));
      }
    }
    // consume B-group (tiles 4-7)
#pragma unroll
    for (int sp = 0; sp < 4; ++sp) {
      int s = 4 + sp;
      uint32_t sel = (s & 1) ? 0x03020302u : 0x01000100u;
#pragma unroll
      for (int mt = 0; mt < 8; ++mt) {
        half8 as_ = splat_mul(a[mt], scu[mt][s >> 1], sel);
        acc[mt][0] = mfma16(as_, gB[sp][0], acc[mt][0]);
        acc[mt][1] = mfma16(as_, gB[sp][1], acc[mt][1]);
      }
    }
    // refill B-group for next block
    if (b < 17) {
#pragma unroll
      for (int sp = 0; sp < 4; ++sp) {
        gB[sp][0] = *(const half8*)(gqn + (lo + (4 + sp) * 16384u));
        gB[sp][1] = *(const half8*)(gqn + (lo + (4 + sp) * 16384u + 1024u));
      }
    }
    gq = gqn;
    e = enext;
  }

  // ---- epilogue: split-K atomic accumulate ----
  const int r0 = rb * 128;
  const int c0 = wid * 32;
#pragma unroll
  for (int mt = 0; mt < 8; ++mt) {
    int rbase = r0 + mt * 16 + (l >> 4) * 4;
#pragma unroll
    for (int nt = 0; nt < 2; ++nt) {
      int c = c0 + nt * 16 + (l & 15);
#pragma unroll
      for (int rg = 0; rg < 4; ++rg)
        atomicAdd(&outp[(size_t)(rbase + rg) * 256 + c], acc[mt][nt][rg]);
    }
  }
}

// ---------------------------------------------------------------------------
// Layer 2 (O=10, one 16-wide n-tile): B global->reg, no barriers in loop.
__global__ __launch_bounds__(512, 2) void qgemm_small(
    const float* __restrict__ hIn, const _Float16* __restrict__ Wt,
    float* __restrict__ outp, const uint32_t* __restrict__ gtab) {
  __shared__ _Float16 hT[128 * 256];
  const int tid = threadIdx.x;
  const int l = tid & 63;
  const int wid = tid >> 6;
  const int kch = blockIdx.x & 7;
  const int rb = blockIdx.x >> 3;
  const int tbase = kch * TPC;

  {
    int r = tid >> 2, sg = tid & 3;
    const float* src = hIn + (size_t)(rb * 128 + r) * 256 + sg * 64;
    char* dst = (char*)hT + r * 512;
    int xo = (r & 7) << 4;
#pragma unroll
    for (int oc = 0; oc < 8; ++oc) {
      float4 f0 = *(const float4*)(src + oc * 8);
      float4 f1 = *(const float4*)(src + oc * 8 + 4);
      half8 hv;
      hv[0] = (_Float16)f0.x; hv[1] = (_Float16)f0.y;
      hv[2] = (_Float16)f0.z; hv[3] = (_Float16)f0.w;
      hv[4] = (_Float16)f1.x; hv[5] = (_Float16)f1.y;
      hv[6] = (_Float16)f1.z; hv[7] = (_Float16)f1.w;
      *(half8*)(dst + ((sg * 128 + oc * 16) ^ xo)) = hv;
    }
  }
  __syncthreads();

  floatx4 acc;
#pragma unroll
  for (int rg = 0; rg < 4; ++rg) acc[rg] = 0.f;

  const int rowb = (wid * 16 + (l & 15)) * 512;
  const int xorb = (l & 7) << 4;
  const int koffA = (l >> 4) * 16;
  const char* hTb = (const char*)hT;

  half8 a, sc;
  int prevjb;

  {
    uint32_t e0 = gtab[tbase];
    int jb = (int)(e0 & 0xFFFFu);
    a = *(const half8*)(hTb + rowb + ((jb * 2 + koffA) ^ xorb));
    half8 b = *(const half8*)(Wt + (size_t)tbase * 512 + l * 8);
    acc = mfma16(a, b, acc);
    prevjb = jb;
  }

  uint32_t e = gtab[tbase + 1];
  for (int u8 = 0; u8 < 18; ++u8) {
    uint32_t enext = (u8 < 17) ? gtab[tbase + 1 + (u8 + 1) * 8] : 0u;
    int i0b = (int)(e >> 16);
    int jb = (int)(e & 0xFFFFu);
    const int ttb = tbase + 1 + u8 * 8;
    half8 bq[8];
#pragma unroll
    for (int s = 0; s < 8; ++s)
      bq[s] = *(const half8*)(Wt + (size_t)(ttb + s) * 512 + l * 8);
    if (jb != prevjb) {
      prevjb = jb;
      a = *(const half8*)(hTb + rowb + ((jb * 2 + koffA) ^ xorb));
    }
    sc = *(const half8*)(hTb + rowb + ((i0b * 2) ^ xorb));
#pragma unroll
    for (int s = 0; s < 8; ++s) {
      _Float16 sv = sc[s];
      half8 sb = {sv, sv, sv, sv, sv, sv, sv, sv};
      acc = mfma16(a * sb, bq[s], acc);
    }
    e = enext;
  }

  const int r0 = rb * 128 + wid * 16 + (l >> 4) * 4;
  const int c = l & 15;
  if (c < 10) {
#pragma unroll
    for (int rg = 0; rg < 4; ++rg)
      atomicAdd(&outp[(size_t)(r0 + rg) * 10 + c], acc[rg]);
  }
}

// ---------------------------------------------------------------------------
extern "C" void kernel_launch(void* const* d_in, const int* in_sizes, int n_in,
                              void* d_out, int out_size, void* d_ws, size_t ws_size,
                              hipStream_t stream) {
  const float* x = (const float*)d_in[0];
  const float* W0 = (const float*)d_in[1];
  const float* b0 = (const float*)d_in[2];
  const float* W1 = (const float*)d_in[3];
  const float* b1 = (const float*)d_in[4];
  const float* W2 = (const float*)d_in[5];
  const float* b2 = (const float*)d_in[6];
  float* out = (float*)d_out;

  char* ws = (char*)d_ws;
  float* h1 = (float*)ws;                                  // 4 MB
  float* h2 = (float*)(ws + (4u << 20));                   // 4 MB
  _Float16* Wt = (_Float16*)(ws + (8u << 20));             // 19,005,440 B
  uint32_t* tab = (uint32_t*)(ws + (8u << 20) + 19005440u);

  build_tab<<<(NTILES + 255) / 256, 256, 0, stream>>>(tab);
  init_out<<<4096, 256, 0, stream>>>(b0, b1, b2, h1, h2, out);

  // layer 0
  convert_w<<<(NTILES * 16 * 64) / 256, 256, 0, stream>>>(W0, Wt, tab, 16, 256);
  qgemm_main<<<256, 512, 0, stream>>>(x, Wt, h1, tab);
  // layer 1
  convert_w<<<(NTILES * 16 * 64) / 256, 256, 0, stream>>>(W1, Wt, tab, 16, 256);
  qgemm_main<<<256, 512, 0, stream>>>(h1, Wt, h2, tab);
  // layer 2
  convert_w<<<(NTILES * 1 * 64 + 255) / 256, 256, 0, stream>>>(W2, Wt, tab, 1, 10);
  qgemm_small<<<256, 512, 0, stream>>>(h2, Wt, out, tab);
}